// Round 1
// baseline (92.569 us; speedup 1.0000x reference)
//
#include <hip/hip_runtime.h>
#include <stdint.h>

// RT-DETR post-processing: per-row top-300 of sigmoid(logits) with exact
// jax.lax.top_k tie semantics (stable: lower index first), plus box affine.
//
// Selection is done on score BITS (scores in (0,1) => positive floats =>
// bit pattern order == value order), composite key (bits<<32)|~idx so that
// rank order == (score desc, index asc) exactly.

#define BATCH 128
#define NCLS 80
#define NQ 2000
#define ROW (NQ * NCLS)   // 160000
#define TOPK 300
#define NB 8192           // level-1 buckets = score_bits >> 17
#define CAP 2048          // candidate buffer
#define NTHR 1024

__device__ __forceinline__ uint32_t score_bits(float x) {
  // stable logistic: x>=0: 1/(1+e^-x) ; x<0: e^x/(1+e^x)
  float e = expf(-fabsf(x));
  float num = (x >= 0.f) ? 1.f : e;
  float s = num / (1.f + e);
  return __float_as_uint(s);
}

__global__ __launch_bounds__(NTHR, 1)
void rtdetr_post_kernel(const float* __restrict__ logits,
                        const float* __restrict__ boxes,
                        const int* __restrict__ sizes,
                        float* __restrict__ out)
{
  __shared__ uint32_t hist[NB];      // 32 KB
  __shared__ uint64_t cand[CAP];     // 16 KB
  __shared__ uint32_t csum[NTHR];    // 4 KB chunk sums (8 buckets/chunk)
  __shared__ uint32_t hist2[256];    // refine path only
  __shared__ uint32_t sh_T, sh_A, sh_T2, sh_cnt;

  const int b = blockIdx.x;
  const int tid = threadIdx.x;
  const float4* row4 = (const float4*)(logits + (size_t)b * ROW);

  for (int i = tid; i < NB; i += NTHR) hist[i] = 0;
  if (tid == 0) sh_cnt = 0;
  __syncthreads();

  // ---- pass 1: histogram of score bits >> 17 ----
  for (int i = tid; i < ROW / 4; i += NTHR) {
    float4 v = row4[i];
    #pragma unroll
    for (int c = 0; c < 4; ++c) {
      uint32_t bits = score_bits((&v.x)[c]);
      uint32_t bk = bits >> 17; bk = bk < NB ? bk : NB - 1;
      atomicAdd(&hist[bk], 1u);
    }
  }
  __syncthreads();

  // ---- chunk sums: each thread sums its 8 buckets ----
  {
    uint32_t s = 0;
    #pragma unroll
    for (int j = 0; j < NB / NTHR; ++j) s += hist[tid * (NB / NTHR) + j];
    csum[tid] = s;
  }
  __syncthreads();

  // ---- wave 0: hierarchical suffix-scan to find threshold bucket ----
  if (tid < 64) {
    const int lane = tid;
    // level 1: 32 superchunks x 32 chunks
    uint32_t ss = 0;
    if (lane < 32) {
      #pragma unroll
      for (int j = 0; j < 32; ++j) ss += csum[lane * 32 + j];
    }
    uint32_t suf = ss;
    #pragma unroll
    for (int d = 1; d < 32; d <<= 1) {
      uint32_t o = __shfl_down(suf, d, 64);
      if (lane + d < 32) suf += o;
    }
    unsigned long long m = __ballot(lane < 32 && suf >= (uint32_t)TOPK);
    int sc = 63 - __builtin_clzll(m);
    uint32_t acc0 = __shfl(suf, sc + 1, 64);   // lane 32 holds 0

    // level 2: 32 chunks inside superchunk sc
    uint32_t cs = (lane < 32) ? csum[sc * 32 + lane] : 0;
    uint32_t suf2 = cs;
    #pragma unroll
    for (int d = 1; d < 32; d <<= 1) {
      uint32_t o = __shfl_down(suf2, d, 64);
      if (lane + d < 32) suf2 += o;
    }
    m = __ballot(lane < 32 && (acc0 + suf2) >= (uint32_t)TOPK);
    int ch = 63 - __builtin_clzll(m);
    uint32_t acc1 = acc0 + __shfl(suf2, ch + 1, 64);
    int chunk = sc * 32 + ch;

    // level 3: 8 buckets inside chunk
    uint32_t hv = (lane < 8) ? hist[chunk * 8 + lane] : 0;
    uint32_t suf3 = hv;
    #pragma unroll
    for (int d = 1; d < 8; d <<= 1) {
      uint32_t o = __shfl_down(suf3, d, 64);
      if (lane + d < 8) suf3 += o;
    }
    m = __ballot(lane < 8 && (acc1 + suf3) >= (uint32_t)TOPK);
    int bk = 63 - __builtin_clzll(m);
    uint32_t A = acc1 + __shfl(suf3, bk + 1, 64);  // strictly-above count
    if (lane == 0) { sh_T = (uint32_t)(chunk * 8 + bk); sh_A = A; }
  }
  __syncthreads();

  const uint32_t T = sh_T;
  const uint32_t A = sh_A;
  const uint32_t C = hist[T];

  // ---- pass 2: collect candidates (bucket >= T) ----
  if (A + C <= CAP) {
    for (int i = tid; i < ROW / 4; i += NTHR) {
      float4 v = row4[i];
      #pragma unroll
      for (int c = 0; c < 4; ++c) {
        uint32_t bits = score_bits((&v.x)[c]);
        uint32_t bk2 = bits >> 17; bk2 = bk2 < NB ? bk2 : NB - 1;
        if (bk2 >= T) {
          uint32_t pos = atomicAdd(&sh_cnt, 1u);
          cand[pos] = ((uint64_t)bits << 32) | (uint32_t)~(uint32_t)(i * 4 + c);
        }
      }
    }
  } else {
    // rare: fat threshold bucket -> refine on next 8 bits
    for (int i = tid; i < 256; i += NTHR) hist2[i] = 0;
    __syncthreads();
    for (int i = tid; i < ROW / 4; i += NTHR) {
      float4 v = row4[i];
      #pragma unroll
      for (int c = 0; c < 4; ++c) {
        uint32_t bits = score_bits((&v.x)[c]);
        uint32_t bk2 = bits >> 17; bk2 = bk2 < NB ? bk2 : NB - 1;
        if (bk2 == T) atomicAdd(&hist2[(bits >> 9) & 0xFF], 1u);
      }
    }
    __syncthreads();
    if (tid < 64) {
      const int lane = tid;
      uint32_t h4 = 0;
      #pragma unroll
      for (int j = 0; j < 4; ++j) h4 += hist2[lane * 4 + j];
      uint32_t suf = h4;
      #pragma unroll
      for (int d = 1; d < 64; d <<= 1) {
        uint32_t o = __shfl_down(suf, d, 64);
        if (lane + d < 64) suf += o;
      }
      unsigned long long m = __ballot((A + suf) >= (uint32_t)TOPK);
      int g = 63 - __builtin_clzll(m);
      uint32_t accg = A + ((g < 63) ? __shfl(suf, g + 1, 64) : 0u);
      uint32_t hb = (lane < 4) ? hist2[g * 4 + lane] : 0;
      uint32_t sufb = hb;
      #pragma unroll
      for (int d = 1; d < 4; d <<= 1) {
        uint32_t o = __shfl_down(sufb, d, 64);
        if (lane + d < 4) sufb += o;
      }
      m = __ballot(lane < 4 && (accg + sufb) >= (uint32_t)TOPK);
      int bin = 63 - __builtin_clzll(m);
      if (lane == 0) sh_T2 = (uint32_t)(g * 4 + bin);
    }
    __syncthreads();
    const uint32_t T2 = sh_T2;
    for (int i = tid; i < ROW / 4; i += NTHR) {
      float4 v = row4[i];
      #pragma unroll
      for (int c = 0; c < 4; ++c) {
        uint32_t bits = score_bits((&v.x)[c]);
        uint32_t bk2 = bits >> 17; bk2 = bk2 < NB ? bk2 : NB - 1;
        bool take = (bk2 > T) || (bk2 == T && ((bits >> 9) & 0xFF) >= T2);
        if (take) {
          uint32_t pos = atomicAdd(&sh_cnt, 1u);
          if (pos < CAP) cand[pos] = ((uint64_t)bits << 32) | (uint32_t)~(uint32_t)(i * 4 + c);
        }
      }
    }
  }
  __syncthreads();

  const uint32_t M = sh_cnt < CAP ? sh_cnt : CAP;

  // ---- exact rank by counting (keys unique), emit top-300 ----
  float* out_labels = out;                                   // [128*300]
  float4* out_boxes = (float4*)(out + BATCH * TOPK);         // [128*300*4]
  float* out_scores = out + BATCH * TOPK + BATCH * TOPK * 4; // [128*300]
  const float4* brow = (const float4*)(boxes + (size_t)b * NQ * 4);
  const float img_h = (float)sizes[2 * b];
  const float img_w = (float)sizes[2 * b + 1];

  for (int i = tid; i < (int)M; i += NTHR) {
    uint64_t key = cand[i];
    int rank = 0;
    for (uint32_t mi = 0; mi < M; ++mi) rank += (cand[mi] > key) ? 1 : 0;
    if (rank < TOPK) {
      uint32_t bits = (uint32_t)(key >> 32);
      uint32_t idx = ~(uint32_t)(key & 0xFFFFFFFFull);
      int q = (int)(idx / NCLS);
      int cls = (int)idx - q * NCLS;
      float4 pb = brow[q];
      float x0 = (pb.x - 0.5f * pb.z) * img_w;
      float y0 = (pb.y - 0.5f * pb.w) * img_h;
      float w2 = pb.z * img_w;
      float h2 = pb.w * img_h;
      x0 = fmaxf(x0, 0.f); y0 = fmaxf(y0, 0.f);
      w2 = fmaxf(w2, 1.f); h2 = fmaxf(h2, 1.f);
      int o = b * TOPK + rank;
      out_labels[o] = (float)cls;
      out_boxes[o] = make_float4(x0, y0, w2, h2);
      out_scores[o] = __uint_as_float(bits);
    }
  }
}

extern "C" void kernel_launch(void* const* d_in, const int* in_sizes, int n_in,
                              void* d_out, int out_size, void* d_ws, size_t ws_size,
                              hipStream_t stream) {
  const float* logits = (const float*)d_in[0];
  const float* boxes  = (const float*)d_in[1];
  const int*   sizes  = (const int*)d_in[2];
  float*       outp   = (float*)d_out;
  (void)in_sizes; (void)n_in; (void)out_size; (void)d_ws; (void)ws_size;
  rtdetr_post_kernel<<<BATCH, NTHR, 0, stream>>>(logits, boxes, sizes, outp);
}